// Round 1
// baseline (283.084 us; speedup 1.0000x reference)
//
#include <hip/hip_runtime.h>
#include <cmath>

// Problem constants (B=1): x (1,4,64,128,128) f32
#define Cc 64
#define Hh 128
#define Ww 128
#define HW_ 16384
#define THW_ 65536
#define CHW_ 1048576
#define NT 27

typedef unsigned short ushort_t;
typedef _Float16 f16x2 __attribute__((ext_vector_type(2)));
typedef _Float16 f16x8 __attribute__((ext_vector_type(8)));
typedef __fp16 fp16x2_alt __attribute__((ext_vector_type(2)));
typedef float floatx4 __attribute__((ext_vector_type(4)));
typedef unsigned uint4v __attribute__((ext_vector_type(4)));

union U32H2 { unsigned u; f16x2 h; };

static __device__ inline ushort_t f2h(float f) {
  union { _Float16 h; ushort_t u; } v;
  v.h = (_Float16)f;
  return v.u;
}

static __device__ inline unsigned pk2(float a) {
  union { fp16x2_alt h; unsigned u; } v;
  v.h = __builtin_amdgcn_cvt_pkrtz(a, a);
  return v.u;
}

#if defined(__has_builtin)
#if __has_builtin(__builtin_amdgcn_make_buffer_rsrc) && __has_builtin(__builtin_amdgcn_raw_buffer_load_b32) && __has_builtin(__builtin_amdgcn_raw_buffer_load_b128)
#define USE_BUF 1
#endif
#endif
#ifndef USE_BUF
#define USE_BUF 0
#endif

struct XtBuf {
#if USE_BUF
  __amdgpu_buffer_rsrc_t r;
#else
  const char* p;
#endif
};

static __device__ inline XtBuf mkbuf(const ushort_t* xt) {
  XtBuf b;
#if USE_BUF
  b.r = __builtin_amdgcn_make_buffer_rsrc((void*)xt, (short)0, 8388608, 0x00020000);
#else
  b.p = (const char*)xt;
#endif
  return b;
}

static __device__ inline uint4v xload4(const XtBuf& b, unsigned voff) {
#if USE_BUF
  return __builtin_amdgcn_raw_buffer_load_b128(b.r, (int)voff, 0, 0);
#else
  return *(const uint4v*)(b.p + voff);
#endif
}

// ws layout (floats):
//   off    : [0, 5308416)           81 * 65536 f32
//   xt     : [5308416, +2097152)    x -> [t][h][w][c] f16 (4194304 ushorts)
//   wfrag  : [7405568, +55296)      deform weight B-frags, 110592 f16
//   w2frag : [7460864, +82944)      offconv weight B-frags, 165888 f16

__global__ __launch_bounds__(256) void prep(
    const float* __restrict__ offset_w,
    const float* __restrict__ weight,
    ushort_t* __restrict__ w2frag,
    ushort_t* __restrict__ wfrag)
{
  int e = blockIdx.x * 256 + threadIdx.x;
  if (e < 165888) {   // offconv: 27 taps x 6 oc-tiles x 2 khalf x 64 lanes x 8
    int j = e & 7, ln = (e >> 3) & 63, kh2 = (e >> 9) & 1, r = e >> 10;
    int ot = r % 6, k = r / 6;
    int oc = ot * 16 + (ln & 15);
    int c  = kh2 * 32 + (ln >> 4) * 8 + j;
    float v = (oc < 81) ? offset_w[(oc * 64 + c) * 27 + k] : 0.f;
    w2frag[e] = f2h(v);
  }
  if (e < 110592) {   // deform: 27 taps x 4 oc-tiles x 2 khalf x 64 lanes x 8
    int j = e & 7, ln = (e >> 3) & 63, kh2 = (e >> 9) & 1, r = e >> 10;
    int ot = r & 3, k = r >> 2;
    int o = ot * 16 + (ln & 15);
    int c = kh2 * 32 + (ln >> 4) * 8 + j;
    wfrag[e] = f2h(weight[(o * 64 + c) * 27 + k]);
  }
}

__global__ __launch_bounds__(256) void transpose_x(
    const float* __restrict__ x, ushort_t* __restrict__ xt)
{
  __shared__ float tile[64][65];
  int b = blockIdx.x;
  int wblk = b & 1;
  int th = b >> 1;
  int h = th & 127;
  int t = th >> 7;
  int w0 = wblk * 64;
  int lane = threadIdx.x & 63;
  int quad = threadIdx.x >> 6;
  #pragma unroll
  for (int cc = 0; cc < 16; ++cc) {
    int c = cc * 4 + quad;
    tile[c][lane] = x[t * CHW_ + c * HW_ + h * Ww + w0 + lane];
  }
  __syncthreads();
  #pragma unroll
  for (int ww = 0; ww < 16; ++ww) {
    int w = ww * 4 + quad;
    xt[(size_t)(t * HW_ + h * Ww + w0 + w) * 64 + lane] = f2h(tile[lane][w]);
  }
}

// Offset conv as MFMA GEMM: off[96 oc (81 used)][64 p] per block, K = 27x64.
// Staging loads are dwordx4 (8 lanes per 128B site row -> 2 VMEM instrs/tap).
__global__ __launch_bounds__(256, 4) void offconv(
    const ushort_t* __restrict__ xt,
    const ushort_t* __restrict__ w2frag,
    const float* __restrict__ ob,
    float* __restrict__ off)
{
  __shared__ __align__(16) char lds[24960];   // S (9216) | Dbuf (24960) aliased
  ushort_t* S = (ushort_t*)lds;               // [64 pos][72 f16]
  float* Dbuf = (float*)lds;                  // [96 oc][65]
  int lane = threadIdx.x & 63;
  int wavei = __builtin_amdgcn_readfirstlane(threadIdx.x >> 6);
  int quad = lane >> 4;
  int m16 = lane & 15;
  int g8 = lane >> 3;
  unsigned coff = (unsigned)((lane & 7) * 16);
  int bid0 = blockIdx.x;
  int p0 = ((bid0 & 7) * 128 + (bid0 >> 3)) * 64;   // XCD swizzle (1024 % 8 == 0)
  int t = p0 >> 14;
  int h = (p0 >> 7) & 127;
  int w0 = p0 & 127;
  XtBuf xb = mkbuf(xt);

  floatx4 acc[6];
  #pragma unroll
  for (int i = 0; i < 6; ++i) acc[i] = (floatx4){0.f, 0.f, 0.f, 0.f};

  uint4v pd[2];

  auto issue = [&](int k) {
    int kt = k / 9, kh = (k / 3) % 3, kw = k % 3;
    int ts = t + kt - 1, hs = h + kh - 1;
    int tsc = min(max(ts, 0), 3);
    int hsc = min(max(hs, 0), 127);
    int sbase = tsc * HW_ + hsc * Ww;
    #pragma unroll
    for (int b = 0; b < 2; ++b) {
      int prow = wavei * 16 + b * 8 + g8;
      int wc = w0 + prow + kw - 1;
      int wcc = min(max(wc, 0), 127);
      pd[b] = xload4(xb, ((unsigned)(sbase + wcc) << 7) + coff);
    }
  };

  issue(0);
  #pragma unroll 1
  for (int k = 0; k < NT; ++k) {
    int kt = k / 9, kh = (k / 3) % 3, kw = k % 3;
    int ts = t + kt - 1, hs = h + kh - 1;
    bool rowok = ((unsigned)ts < 4u) && ((unsigned)hs < 128u);
    // write current tap's staged loads to S (masked, b128)
    #pragma unroll
    for (int b = 0; b < 2; ++b) {
      int prow = wavei * 16 + b * 8 + g8;
      int wc = w0 + prow + kw - 1;
      bool ok = rowok && ((unsigned)wc < 128u);
      uint4v v = pd[b];
      if (!ok) v = (uint4v){0u, 0u, 0u, 0u};
      *(uint4v*)((char*)S + prow * 144 + coff) = v;
    }
    // issue next tap's loads (in flight during MFMAs)
    issue(k + 1 < NT ? k + 1 : NT - 1);
    const ushort_t* srow = S + (wavei * 16 + m16) * 72 + quad * 8;
    f16x8 af0 = *(const f16x8*)srow;
    f16x8 af1 = *(const f16x8*)(srow + 32);
    #pragma unroll
    for (int ot = 0; ot < 6; ++ot) {
      const ushort_t* wb = w2frag + (size_t)((k * 6 + ot) * 2) * 512 + lane * 8;
      f16x8 b0 = *(const f16x8*)(wb);
      f16x8 b1 = *(const f16x8*)(wb + 512);
      acc[ot] = __builtin_amdgcn_mfma_f32_16x16x32_f16(af0, b0, acc[ot], 0, 0, 0);
      acc[ot] = __builtin_amdgcn_mfma_f32_16x16x32_f16(af1, b1, acc[ot], 0, 0, 0);
    }
  }
  __syncthreads();   // S dead; Dbuf aliases it
  #pragma unroll
  for (int ot = 0; ot < 6; ++ot)
    #pragma unroll
    for (int r = 0; r < 4; ++r)
      Dbuf[(ot * 16 + m16) * 65 + wavei * 16 + quad * 4 + r] = acc[ot][r];
  __syncthreads();
  for (int i = threadIdx.x; i < 81 * 64; i += 256) {
    int oc = i >> 6, p = i & 63;
    off[(size_t)oc * THW_ + p0 + p] = Dbuf[oc * 65 + p] + ob[oc];
  }
}

// One trilinear site: data chunk (uint4v = 8 f16 ch) x packed weight, into
// even/odd f16x2 accumulator chains (bit-identical order to previous kernel).
#define SITE(W, D, A0, A1, A2, A3) \
  { U32H2 wu; wu.u = (W); U32H2 q0, q1, q2, q3; \
    q0.u = (D)[0]; q1.u = (D)[1]; q2.u = (D)[2]; q3.u = (D)[3]; \
    A0 += wu.h * q0.h; A1 += wu.h * q1.h; A2 += wu.h * q2.h; A3 += wu.h * q3.h; }

// Deformable sample + MFMA GEMM: out[64 oc][64 p] per block, K = 27x64.
// Gather is dwordx4 (8 lanes per 128B site row): 16 VMEM instrs/tap, all 16
// staged in registers before consumption (one latency exposure per tap).
__global__ __launch_bounds__(256, 3) void deform(
    const float* __restrict__ x,
    const ushort_t* __restrict__ xt,
    const float* __restrict__ off,
    const ushort_t* __restrict__ wfrag,
    const float* __restrict__ gamma,
    float* __restrict__ out)
{
  __shared__ __align__(16) char lds[16640];   // S(9216)+msite(2048)+mwt(2048) | Dbuf
  ushort_t* S = (ushort_t*)lds;               // [64 pos][72 f16]
  unsigned* msite = (unsigned*)(lds + 9216);  // [64 pos][8]
  unsigned* mwt   = (unsigned*)(lds + 11264); // [64 pos][8]
  float* Dbuf = (float*)lds;                  // [64 oc][65]
  int lane = threadIdx.x & 63;
  int wavei = __builtin_amdgcn_readfirstlane(threadIdx.x >> 6);
  int quad = lane >> 4;
  int m16 = lane & 15;
  int g8 = lane >> 3;
  unsigned coff = (unsigned)((lane & 7) * 16);
  int bid0 = blockIdx.x;
  int p0 = ((bid0 & 7) * 128 + (bid0 >> 3)) * 64;   // XCD swizzle
  int t = p0 >> 14;
  int h = (p0 >> 7) & 127;
  int w0 = p0 & 127;
  XtBuf xb = mkbuf(xt);

  floatx4 acc[4];
  #pragma unroll
  for (int i = 0; i < 4; ++i) acc[i] = (floatx4){0.f, 0.f, 0.f, 0.f};

  int pl = wavei * 16 + m16;
  int pm = p0 + pl;
  int aq = quad >> 1, bq = quad & 1;
  int rowA = wavei * 16 + g8;
  int rowB = rowA + 8;
  const float* offT = off + pm;

  float dt_c = offT[(size_t)(0 * NT + 0) * THW_];
  float dh_c = offT[(size_t)(1 * NT + 0) * THW_];
  float dw_c = offT[(size_t)(2 * NT + 0) * THW_];

  #pragma unroll 1
  for (int k = 0; k < NT; ++k) {
    int kn = (k + 1 < NT) ? k + 1 : NT - 1;
    float dt_n = offT[(size_t)(0 * NT + kn) * THW_];
    float dh_n = offT[(size_t)(1 * NT + kn) * THW_];
    float dw_n = offT[(size_t)(2 * NT + kn) * THW_];

    int kt = k / 9, kh = (k / 3) % 3, kw = k % 3;
    // --- meta: lane handles position pl, (t,h)-corner (aq,bq), both w-corners
    float tf = (float)(t + kt - 1) + dt_c;
    float hf = (float)(h + kh - 1) + dh_c;
    float wf = (float)(w0 + pl + kw - 1) + dw_c;
    float tF = floorf(tf), hF = floorf(hf), wF = floorf(wf);
    float lt = tf - tF, lh_ = hf - hF, lw_ = wf - wF;
    int t0 = (int)tF, h0 = (int)hF, wq_ = (int)wF;
    int ti = t0 + aq;
    float wt_ = (aq ? lt : 1.f - lt) * (((unsigned)ti < 4u) ? 1.f : 0.f);
    int tic = min(max(ti, 0), 3);
    int hi = h0 + bq;
    float wh_ = (bq ? lh_ : 1.f - lh_) * (((unsigned)hi < 128u) ? 1.f : 0.f);
    int hic = min(max(hi, 0), 127);
    int base2 = tic * HW_ + hic * Ww;
    float bw = wt_ * wh_;
    int wi0 = wq_;
    float ww0 = (1.f - lw_) * (((unsigned)wi0 < 128u) ? 1.f : 0.f);
    int wi0c = min(max(wi0, 0), 127);
    int wi1 = wq_ + 1;
    float ww1 = lw_ * (((unsigned)wi1 < 128u) ? 1.f : 0.f);
    int wi1c = min(max(wi1, 0), 127);
    uint2 sp_;
    sp_.x = (unsigned)(base2 + wi0c) << 7;
    sp_.y = (unsigned)(base2 + wi1c) << 7;
    *(uint2*)&msite[pl * 8 + quad * 2] = sp_;
    uint2 wp_;
    wp_.x = pk2(bw * ww0);
    wp_.y = pk2(bw * ww1);
    *(uint2*)&mwt[pl * 8 + quad * 2] = wp_;

    // --- phase 1: issue all 16 gather loads (x4) into register stage
    const uint4* spA = (const uint4*)&msite[rowA * 8];
    uint4 sA0 = spA[0], sA1 = spA[1];
    const uint4* spB = (const uint4*)&msite[rowB * 8];
    uint4 sB0 = spB[0], sB1 = spB[1];
    uint4v stA0 = xload4(xb, sA0.x + coff);
    uint4v stA1 = xload4(xb, sA0.y + coff);
    uint4v stA2 = xload4(xb, sA0.z + coff);
    uint4v stA3 = xload4(xb, sA0.w + coff);
    uint4v stA4 = xload4(xb, sA1.x + coff);
    uint4v stA5 = xload4(xb, sA1.y + coff);
    uint4v stA6 = xload4(xb, sA1.z + coff);
    uint4v stA7 = xload4(xb, sA1.w + coff);
    uint4v stB0 = xload4(xb, sB0.x + coff);
    uint4v stB1 = xload4(xb, sB0.y + coff);
    uint4v stB2 = xload4(xb, sB0.z + coff);
    uint4v stB3 = xload4(xb, sB0.w + coff);
    uint4v stB4 = xload4(xb, sB1.x + coff);
    uint4v stB5 = xload4(xb, sB1.y + coff);
    uint4v stB6 = xload4(xb, sB1.z + coff);
    uint4v stB7 = xload4(xb, sB1.w + coff);

    // --- phase 2: consume in issue order
    {
      const uint4* wpA = (const uint4*)&mwt[rowA * 8];
      uint4 w03 = wpA[0], w47 = wpA[1];
      U32H2 z; z.u = 0;
      f16x2 e0 = z.h, e1 = z.h, e2 = z.h, e3 = z.h;
      f16x2 o0 = z.h, o1 = z.h, o2 = z.h, o3 = z.h;
      SITE(w03.x, stA0, e0, e1, e2, e3)
      SITE(w03.y, stA1, o0, o1, o2, o3)
      SITE(w03.z, stA2, e0, e1, e2, e3)
      SITE(w03.w, stA3, o0, o1, o2, o3)
      SITE(w47.x, stA4, e0, e1, e2, e3)
      SITE(w47.y, stA5, o0, o1, o2, o3)
      SITE(w47.z, stA6, e0, e1, e2, e3)
      SITE(w47.w, stA7, o0, o1, o2, o3)
      U32H2 r0, r1, r2, r3;
      r0.h = e0 + o0; r1.h = e1 + o1; r2.h = e2 + o2; r3.h = e3 + o3;
      uint4v res = {r0.u, r1.u, r2.u, r3.u};
      *(uint4v*)((char*)S + rowA * 144 + coff) = res;
    }
    {
      const uint4* wpB = (const uint4*)&mwt[rowB * 8];
      uint4 w03 = wpB[0], w47 = wpB[1];
      U32H2 z; z.u = 0;
      f16x2 e0 = z.h, e1 = z.h, e2 = z.h, e3 = z.h;
      f16x2 o0 = z.h, o1 = z.h, o2 = z.h, o3 = z.h;
      SITE(w03.x, stB0, e0, e1, e2, e3)
      SITE(w03.y, stB1, o0, o1, o2, o3)
      SITE(w03.z, stB2, e0, e1, e2, e3)
      SITE(w03.w, stB3, o0, o1, o2, o3)
      SITE(w47.x, stB4, e0, e1, e2, e3)
      SITE(w47.y, stB5, o0, o1, o2, o3)
      SITE(w47.z, stB6, e0, e1, e2, e3)
      SITE(w47.w, stB7, o0, o1, o2, o3)
      U32H2 r0, r1, r2, r3;
      r0.h = e0 + o0; r1.h = e1 + o1; r2.h = e2 + o2; r3.h = e3 + o3;
      uint4v res = {r0.u, r1.u, r2.u, r3.u};
      *(uint4v*)((char*)S + rowB * 144 + coff) = res;
    }

    // --- MFMA
    const ushort_t* srow = S + (wavei * 16 + m16) * 72 + quad * 8;
    f16x8 af0 = *(const f16x8*)srow;
    f16x8 af1 = *(const f16x8*)(srow + 32);
    #pragma unroll
    for (int ot = 0; ot < 4; ++ot) {
      const ushort_t* wb = wfrag + (size_t)((k * 4 + ot) * 2) * 512 + lane * 8;
      f16x8 b0 = *(const f16x8*)(wb);
      f16x8 b1 = *(const f16x8*)(wb + 512);
      acc[ot] = __builtin_amdgcn_mfma_f32_16x16x32_f16(af0, b0, acc[ot], 0, 0, 0);
      acc[ot] = __builtin_amdgcn_mfma_f32_16x16x32_f16(af1, b1, acc[ot], 0, 0, 0);
    }
    dt_c = dt_n; dh_c = dh_n; dw_c = dw_n;
  }
  __syncthreads();   // S/meta dead; Dbuf aliases them
  #pragma unroll
  for (int ot = 0; ot < 4; ++ot)
    #pragma unroll
    for (int r = 0; r < 4; ++r)
      Dbuf[(ot * 16 + m16) * 65 + wavei * 16 + quad * 4 + r] = acc[ot][r];
  __syncthreads();
  float g = gamma[0];
  for (int i = threadIdx.x; i < 64 * 64; i += 256) {
    int oc = i >> 6, p = i & 63;
    size_t oi = (size_t)t * CHW_ + (size_t)oc * HW_ + (size_t)h * Ww + w0 + p;
    out[oi] = fmaf(g, Dbuf[oc * 65 + p], x[oi]);
  }
}

extern "C" void kernel_launch(void* const* d_in, const int* in_sizes, int n_in,
                              void* d_out, int out_size, void* d_ws, size_t ws_size,
                              hipStream_t stream) {
  (void)in_sizes; (void)n_in; (void)out_size; (void)ws_size;
  const float* x        = (const float*)d_in[0];
  const float* offset_w = (const float*)d_in[1];
  const float* offset_b = (const float*)d_in[2];
  const float* weight   = (const float*)d_in[3];
  const float* gamma    = (const float*)d_in[4];
  float* out = (float*)d_out;
  float* wsf = (float*)d_ws;
  float*    off    = wsf;                               // 5308416 f32
  ushort_t* xt     = (ushort_t*)(wsf + 5308416);        // 4194304 f16
  ushort_t* wfrag  = (ushort_t*)(wsf + 7405568);        // 110592 f16
  ushort_t* w2frag = (ushort_t*)(wsf + 7460864);        // 165888 f16

  hipLaunchKernelGGL(prep, dim3(648), dim3(256), 0, stream,
                     offset_w, weight, w2frag, wfrag);
  hipLaunchKernelGGL(transpose_x, dim3(1024), dim3(256), 0, stream, x, xt);
  hipLaunchKernelGGL(offconv, dim3(1024), dim3(256), 0, stream,
                     xt, w2frag, offset_b, off);
  hipLaunchKernelGGL(deform, dim3(1024), dim3(256), 0, stream,
                     x, xt, off, wfrag, gamma, out);
}

// Round 2
// 224.609 us; speedup vs baseline: 1.2603x; 1.2603x over previous
//
#include <hip/hip_runtime.h>
#include <cmath>

// Problem constants (B=1): x (1,4,64,128,128) f32
#define Cc 64
#define Hh 128
#define Ww 128
#define HW_ 16384
#define THW_ 65536
#define CHW_ 1048576
#define NT 27

typedef unsigned short ushort_t;
typedef _Float16 f16x2 __attribute__((ext_vector_type(2)));
typedef _Float16 f16x8 __attribute__((ext_vector_type(8)));
typedef __fp16 fp16x2_alt __attribute__((ext_vector_type(2)));
typedef float floatx4 __attribute__((ext_vector_type(4)));
typedef unsigned uint4v __attribute__((ext_vector_type(4)));

union U32H2 { unsigned u; f16x2 h; };

static __device__ inline ushort_t f2h(float f) {
  union { _Float16 h; ushort_t u; } v;
  v.h = (_Float16)f;
  return v.u;
}

static __device__ inline unsigned pk2(float a) {
  union { fp16x2_alt h; unsigned u; } v;
  v.h = __builtin_amdgcn_cvt_pkrtz(a, a);
  return v.u;
}

#if defined(__has_builtin)
#if __has_builtin(__builtin_amdgcn_make_buffer_rsrc) && __has_builtin(__builtin_amdgcn_raw_buffer_load_b32) && __has_builtin(__builtin_amdgcn_raw_buffer_load_b128)
#define USE_BUF 1
#endif
#endif
#ifndef USE_BUF
#define USE_BUF 0
#endif

struct XtBuf {
#if USE_BUF
  __amdgpu_buffer_rsrc_t r;
#else
  const char* p;
#endif
};

static __device__ inline XtBuf mkbuf(const ushort_t* xt) {
  XtBuf b;
#if USE_BUF
  b.r = __builtin_amdgcn_make_buffer_rsrc((void*)xt, (short)0, 8388608, 0x00020000);
#else
  b.p = (const char*)xt;
#endif
  return b;
}

static __device__ inline uint4v xload4(const XtBuf& b, unsigned voff) {
#if USE_BUF
  return __builtin_amdgcn_raw_buffer_load_b128(b.r, (int)voff, 0, 0);
#else
  return *(const uint4v*)(b.p + voff);
#endif
}

// ws layout (floats):
//   off    : [0, 5308416)           81 * 65536 f32
//   xt     : [5308416, +2097152)    x -> [t][h][w][c] f16 (4194304 ushorts)
//   wfrag  : [7405568, +55296)      deform weight B-frags, 110592 f16
//   w2frag : [7460864, +82944)      offconv weight B-frags, 165888 f16

__global__ __launch_bounds__(256) void prep(
    const float* __restrict__ offset_w,
    const float* __restrict__ weight,
    ushort_t* __restrict__ w2frag,
    ushort_t* __restrict__ wfrag)
{
  int e = blockIdx.x * 256 + threadIdx.x;
  if (e < 165888) {   // offconv: 27 taps x 6 oc-tiles x 2 khalf x 64 lanes x 8
    int j = e & 7, ln = (e >> 3) & 63, kh2 = (e >> 9) & 1, r = e >> 10;
    int ot = r % 6, k = r / 6;
    int oc = ot * 16 + (ln & 15);
    int c  = kh2 * 32 + (ln >> 4) * 8 + j;
    float v = (oc < 81) ? offset_w[(oc * 64 + c) * 27 + k] : 0.f;
    w2frag[e] = f2h(v);
  }
  if (e < 110592) {   // deform: 27 taps x 4 oc-tiles x 2 khalf x 64 lanes x 8
    int j = e & 7, ln = (e >> 3) & 63, kh2 = (e >> 9) & 1, r = e >> 10;
    int ot = r & 3, k = r >> 2;
    int o = ot * 16 + (ln & 15);
    int c = kh2 * 32 + (ln >> 4) * 8 + j;
    wfrag[e] = f2h(weight[(o * 64 + c) * 27 + k]);
  }
}

__global__ __launch_bounds__(256) void transpose_x(
    const float* __restrict__ x, ushort_t* __restrict__ xt)
{
  __shared__ float tile[64][65];
  int b = blockIdx.x;
  int wblk = b & 1;
  int th = b >> 1;
  int h = th & 127;
  int t = th >> 7;
  int w0 = wblk * 64;
  int lane = threadIdx.x & 63;
  int quad = threadIdx.x >> 6;
  #pragma unroll
  for (int cc = 0; cc < 16; ++cc) {
    int c = cc * 4 + quad;
    tile[c][lane] = x[t * CHW_ + c * HW_ + h * Ww + w0 + lane];
  }
  __syncthreads();
  #pragma unroll
  for (int ww = 0; ww < 16; ++ww) {
    int w = ww * 4 + quad;
    xt[(size_t)(t * HW_ + h * Ww + w0 + w) * 64 + lane] = f2h(tile[lane][w]);
  }
}

// Offset conv as MFMA GEMM: off[96 oc (81 used)][64 p] per block, K = 27x64.
// Staging loads are dwordx4 (8 lanes per 128B site row -> 2 VMEM instrs/tap).
__global__ __launch_bounds__(256, 4) void offconv(
    const ushort_t* __restrict__ xt,
    const ushort_t* __restrict__ w2frag,
    const float* __restrict__ ob,
    float* __restrict__ off)
{
  __shared__ __align__(16) char lds[24960];   // S (9216) | Dbuf (24960) aliased
  ushort_t* S = (ushort_t*)lds;               // [64 pos][72 f16]
  float* Dbuf = (float*)lds;                  // [96 oc][65]
  int lane = threadIdx.x & 63;
  int wavei = __builtin_amdgcn_readfirstlane(threadIdx.x >> 6);
  int quad = lane >> 4;
  int m16 = lane & 15;
  int g8 = lane >> 3;
  unsigned coff = (unsigned)((lane & 7) * 16);
  int bid0 = blockIdx.x;
  int p0 = ((bid0 & 7) * 128 + (bid0 >> 3)) * 64;   // XCD swizzle (1024 % 8 == 0)
  int t = p0 >> 14;
  int h = (p0 >> 7) & 127;
  int w0 = p0 & 127;
  XtBuf xb = mkbuf(xt);

  floatx4 acc[6];
  #pragma unroll
  for (int i = 0; i < 6; ++i) acc[i] = (floatx4){0.f, 0.f, 0.f, 0.f};

  uint4v pd[2];

  auto issue = [&](int k) {
    int kt = k / 9, kh = (k / 3) % 3, kw = k % 3;
    int ts = t + kt - 1, hs = h + kh - 1;
    int tsc = min(max(ts, 0), 3);
    int hsc = min(max(hs, 0), 127);
    int sbase = tsc * HW_ + hsc * Ww;
    #pragma unroll
    for (int b = 0; b < 2; ++b) {
      int prow = wavei * 16 + b * 8 + g8;
      int wc = w0 + prow + kw - 1;
      int wcc = min(max(wc, 0), 127);
      pd[b] = xload4(xb, ((unsigned)(sbase + wcc) << 7) + coff);
    }
  };

  issue(0);
  #pragma unroll 1
  for (int k = 0; k < NT; ++k) {
    int kt = k / 9, kh = (k / 3) % 3, kw = k % 3;
    int ts = t + kt - 1, hs = h + kh - 1;
    bool rowok = ((unsigned)ts < 4u) && ((unsigned)hs < 128u);
    // write current tap's staged loads to S (masked, b128)
    #pragma unroll
    for (int b = 0; b < 2; ++b) {
      int prow = wavei * 16 + b * 8 + g8;
      int wc = w0 + prow + kw - 1;
      bool ok = rowok && ((unsigned)wc < 128u);
      uint4v v = pd[b];
      if (!ok) v = (uint4v){0u, 0u, 0u, 0u};
      *(uint4v*)((char*)S + prow * 144 + coff) = v;
    }
    // issue next tap's loads (in flight during MFMAs)
    issue(k + 1 < NT ? k + 1 : NT - 1);
    const ushort_t* srow = S + (wavei * 16 + m16) * 72 + quad * 8;
    f16x8 af0 = *(const f16x8*)srow;
    f16x8 af1 = *(const f16x8*)(srow + 32);
    #pragma unroll
    for (int ot = 0; ot < 6; ++ot) {
      const ushort_t* wb = w2frag + (size_t)((k * 6 + ot) * 2) * 512 + lane * 8;
      f16x8 b0 = *(const f16x8*)(wb);
      f16x8 b1 = *(const f16x8*)(wb + 512);
      acc[ot] = __builtin_amdgcn_mfma_f32_16x16x32_f16(af0, b0, acc[ot], 0, 0, 0);
      acc[ot] = __builtin_amdgcn_mfma_f32_16x16x32_f16(af1, b1, acc[ot], 0, 0, 0);
    }
  }
  __syncthreads();   // S dead; Dbuf aliases it
  #pragma unroll
  for (int ot = 0; ot < 6; ++ot)
    #pragma unroll
    for (int r = 0; r < 4; ++r)
      Dbuf[(ot * 16 + m16) * 65 + wavei * 16 + quad * 4 + r] = acc[ot][r];
  __syncthreads();
  for (int i = threadIdx.x; i < 81 * 64; i += 256) {
    int oc = i >> 6, p = i & 63;
    off[(size_t)oc * THW_ + p0 + p] = Dbuf[oc * 65 + p] + ob[oc];
  }
}

// One trilinear site: data chunk (uint4v = 8 f16 ch) x packed weight, into
// even/odd f16x2 accumulator chains (bit-identical order to the 107us kernel).
#define SITE(W, D, A0, A1, A2, A3) \
  { U32H2 wu; wu.u = (W); U32H2 q0, q1, q2, q3; \
    q0.u = (D)[0]; q1.u = (D)[1]; q2.u = (D)[2]; q3.u = (D)[3]; \
    A0 += wu.h * q0.h; A1 += wu.h * q1.h; A2 += wu.h * q2.h; A3 += wu.h * q3.h; }

// Deformable sample + MFMA GEMM: out[64 oc][64 p] per block, K = 27x64.
// Half-tap software pipeline: while half-A of tap k is consumed, half-B's 8
// dwordx4 gathers are in flight; while tap k's MFMAs run, half-A of tap k+1
// is in flight. sched_barrier(0) fences pin the issue/consume split so the
// compiler cannot sink the loads (round-1 failure mode: VGPR=32, serialized).
// Meta (msite/mwt) double-buffered by tap parity since tap k+1's meta is
// computed inside iteration k.
__global__ __launch_bounds__(256, 4) void deform(
    const float* __restrict__ x,
    const ushort_t* __restrict__ xt,
    const float* __restrict__ off,
    const ushort_t* __restrict__ wfrag,
    const float* __restrict__ gamma,
    float* __restrict__ out)
{
  __shared__ __align__(16) char lds[17408];   // S(9216)+msite[2](4096)+mwt[2](4096) | Dbuf(16640)
  ushort_t* S = (ushort_t*)lds;               // [64 pos][72 f16]
  unsigned* msite0 = (unsigned*)(lds + 9216);
  unsigned* msite1 = (unsigned*)(lds + 11264);
  unsigned* mwt0   = (unsigned*)(lds + 13312);
  unsigned* mwt1   = (unsigned*)(lds + 15360);
  float* Dbuf = (float*)lds;                  // [64 oc][65]
  int lane = threadIdx.x & 63;
  int wavei = __builtin_amdgcn_readfirstlane(threadIdx.x >> 6);
  int quad = lane >> 4;
  int m16 = lane & 15;
  int g8 = lane >> 3;
  unsigned coff = (unsigned)((lane & 7) * 16);
  int bid0 = blockIdx.x;
  int p0 = ((bid0 & 7) * 128 + (bid0 >> 3)) * 64;   // XCD swizzle
  int t = p0 >> 14;
  int h = (p0 >> 7) & 127;
  int w0 = p0 & 127;
  XtBuf xb = mkbuf(xt);

  floatx4 acc[4];
  #pragma unroll
  for (int i = 0; i < 4; ++i) acc[i] = (floatx4){0.f, 0.f, 0.f, 0.f};

  int pl = wavei * 16 + m16;
  int pm = p0 + pl;
  int aq = quad >> 1, bq = quad & 1;
  int rowA = wavei * 16 + g8;
  int rowB = rowA + 8;
  const float* offT = off + pm;

  uint4v stA[8], stB[8];

  // meta for tap kk -> buffers [kk&1]; bit-identical math to the 107us kernel
  auto meta = [&](int kk, float dtv, float dhv, float dwv) {
    unsigned* ms = (kk & 1) ? msite1 : msite0;
    unsigned* mw = (kk & 1) ? mwt1 : mwt0;
    int kt = kk / 9, kh = (kk / 3) % 3, kw = kk % 3;
    float tf = (float)(t + kt - 1) + dtv;
    float hf = (float)(h + kh - 1) + dhv;
    float wf = (float)(w0 + pl + kw - 1) + dwv;
    float tF = floorf(tf), hF = floorf(hf), wF = floorf(wf);
    float lt = tf - tF, lh_ = hf - hF, lw_ = wf - wF;
    int t0 = (int)tF, h0 = (int)hF, wq_ = (int)wF;
    int ti = t0 + aq;
    float wt_ = (aq ? lt : 1.f - lt) * (((unsigned)ti < 4u) ? 1.f : 0.f);
    int tic = min(max(ti, 0), 3);
    int hi = h0 + bq;
    float wh_ = (bq ? lh_ : 1.f - lh_) * (((unsigned)hi < 128u) ? 1.f : 0.f);
    int hic = min(max(hi, 0), 127);
    int base2 = tic * HW_ + hic * Ww;
    float bw = wt_ * wh_;
    int wi0 = wq_;
    float ww0 = (1.f - lw_) * (((unsigned)wi0 < 128u) ? 1.f : 0.f);
    int wi0c = min(max(wi0, 0), 127);
    int wi1 = wq_ + 1;
    float ww1 = lw_ * (((unsigned)wi1 < 128u) ? 1.f : 0.f);
    int wi1c = min(max(wi1, 0), 127);
    uint2 sp_;
    sp_.x = (unsigned)(base2 + wi0c) << 7;
    sp_.y = (unsigned)(base2 + wi1c) << 7;
    *(uint2*)&ms[pl * 8 + quad * 2] = sp_;
    uint2 wp_;
    wp_.x = pk2(bw * ww0);
    wp_.y = pk2(bw * ww1);
    *(uint2*)&mw[pl * 8 + quad * 2] = wp_;
  };

  auto issueA = [&](int kk) {
    const unsigned* ms = (kk & 1) ? msite1 : msite0;
    const uint4* sp = (const uint4*)&ms[rowA * 8];
    uint4 s0 = sp[0], s1 = sp[1];
    stA[0] = xload4(xb, s0.x + coff);
    stA[1] = xload4(xb, s0.y + coff);
    stA[2] = xload4(xb, s0.z + coff);
    stA[3] = xload4(xb, s0.w + coff);
    stA[4] = xload4(xb, s1.x + coff);
    stA[5] = xload4(xb, s1.y + coff);
    stA[6] = xload4(xb, s1.z + coff);
    stA[7] = xload4(xb, s1.w + coff);
  };
  auto issueB = [&](int kk) {
    const unsigned* ms = (kk & 1) ? msite1 : msite0;
    const uint4* sp = (const uint4*)&ms[rowB * 8];
    uint4 s0 = sp[0], s1 = sp[1];
    stB[0] = xload4(xb, s0.x + coff);
    stB[1] = xload4(xb, s0.y + coff);
    stB[2] = xload4(xb, s0.z + coff);
    stB[3] = xload4(xb, s0.w + coff);
    stB[4] = xload4(xb, s1.x + coff);
    stB[5] = xload4(xb, s1.y + coff);
    stB[6] = xload4(xb, s1.z + coff);
    stB[7] = xload4(xb, s1.w + coff);
  };

  auto consumeA = [&](int kk) {
    const unsigned* mw = (kk & 1) ? mwt1 : mwt0;
    const uint4* wp = (const uint4*)&mw[rowA * 8];
    uint4 w03 = wp[0], w47 = wp[1];
    U32H2 z; z.u = 0;
    f16x2 e0 = z.h, e1 = z.h, e2 = z.h, e3 = z.h;
    f16x2 o0 = z.h, o1 = z.h, o2 = z.h, o3 = z.h;
    SITE(w03.x, stA[0], e0, e1, e2, e3)
    SITE(w03.y, stA[1], o0, o1, o2, o3)
    SITE(w03.z, stA[2], e0, e1, e2, e3)
    SITE(w03.w, stA[3], o0, o1, o2, o3)
    SITE(w47.x, stA[4], e0, e1, e2, e3)
    SITE(w47.y, stA[5], o0, o1, o2, o3)
    SITE(w47.z, stA[6], e0, e1, e2, e3)
    SITE(w47.w, stA[7], o0, o1, o2, o3)
    U32H2 r0, r1, r2, r3;
    r0.h = e0 + o0; r1.h = e1 + o1; r2.h = e2 + o2; r3.h = e3 + o3;
    uint4v res = {r0.u, r1.u, r2.u, r3.u};
    *(uint4v*)((char*)S + rowA * 144 + coff) = res;
  };
  auto consumeB = [&](int kk) {
    const unsigned* mw = (kk & 1) ? mwt1 : mwt0;
    const uint4* wp = (const uint4*)&mw[rowB * 8];
    uint4 w03 = wp[0], w47 = wp[1];
    U32H2 z; z.u = 0;
    f16x2 e0 = z.h, e1 = z.h, e2 = z.h, e3 = z.h;
    f16x2 o0 = z.h, o1 = z.h, o2 = z.h, o3 = z.h;
    SITE(w03.x, stB[0], e0, e1, e2, e3)
    SITE(w03.y, stB[1], o0, o1, o2, o3)
    SITE(w03.z, stB[2], e0, e1, e2, e3)
    SITE(w03.w, stB[3], o0, o1, o2, o3)
    SITE(w47.x, stB[4], e0, e1, e2, e3)
    SITE(w47.y, stB[5], o0, o1, o2, o3)
    SITE(w47.z, stB[6], e0, e1, e2, e3)
    SITE(w47.w, stB[7], o0, o1, o2, o3)
    U32H2 r0, r1, r2, r3;
    r0.h = e0 + o0; r1.h = e1 + o1; r2.h = e2 + o2; r3.h = e3 + o3;
    uint4v res = {r0.u, r1.u, r2.u, r3.u};
    *(uint4v*)((char*)S + rowB * 144 + coff) = res;
  };

  // prologue: meta(0) then half-A(0) in flight
  float dt0 = offT[(size_t)(0 * NT + 0) * THW_];
  float dh0 = offT[(size_t)(1 * NT + 0) * THW_];
  float dw0 = offT[(size_t)(2 * NT + 0) * THW_];
  meta(0, dt0, dh0, dw0);
  issueA(0);

  #pragma unroll 1
  for (int k = 0; k < NT; ++k) {
    int kn = (k + 1 < NT) ? k + 1 : NT - 1;
    float dt_n = offT[(size_t)(0 * NT + kn) * THW_];
    float dh_n = offT[(size_t)(1 * NT + kn) * THW_];
    float dw_n = offT[(size_t)(2 * NT + kn) * THW_];

    issueB(k);                               // half-B in flight over consumeA+meta
    __builtin_amdgcn_sched_barrier(0);
    consumeA(k);                             // S rows [0..8)
    meta(kn, dt_n, dh_n, dw_n);              // tap k+1 meta -> buf (kn&1)
    consumeB(k);                             // S rows [8..16)
    issueA(kn);                              // half-A(k+1) in flight over MFMAs
    __builtin_amdgcn_sched_barrier(0);

    // --- MFMA
    const ushort_t* srow = S + (wavei * 16 + m16) * 72 + quad * 8;
    f16x8 af0 = *(const f16x8*)srow;
    f16x8 af1 = *(const f16x8*)(srow + 32);
    #pragma unroll
    for (int ot = 0; ot < 4; ++ot) {
      const ushort_t* wb = wfrag + (size_t)((k * 4 + ot) * 2) * 512 + lane * 8;
      f16x8 b0 = *(const f16x8*)(wb);
      f16x8 b1 = *(const f16x8*)(wb + 512);
      acc[ot] = __builtin_amdgcn_mfma_f32_16x16x32_f16(af0, b0, acc[ot], 0, 0, 0);
      acc[ot] = __builtin_amdgcn_mfma_f32_16x16x32_f16(af1, b1, acc[ot], 0, 0, 0);
    }
  }
  __syncthreads();   // S/meta dead; Dbuf aliases them
  #pragma unroll
  for (int ot = 0; ot < 4; ++ot)
    #pragma unroll
    for (int r = 0; r < 4; ++r)
      Dbuf[(ot * 16 + m16) * 65 + wavei * 16 + quad * 4 + r] = acc[ot][r];
  __syncthreads();
  float g = gamma[0];
  for (int i = threadIdx.x; i < 64 * 64; i += 256) {
    int oc = i >> 6, p = i & 63;
    size_t oi = (size_t)t * CHW_ + (size_t)oc * HW_ + (size_t)h * Ww + w0 + p;
    out[oi] = fmaf(g, Dbuf[oc * 65 + p], x[oi]);
  }
}

extern "C" void kernel_launch(void* const* d_in, const int* in_sizes, int n_in,
                              void* d_out, int out_size, void* d_ws, size_t ws_size,
                              hipStream_t stream) {
  (void)in_sizes; (void)n_in; (void)out_size; (void)ws_size;
  const float* x        = (const float*)d_in[0];
  const float* offset_w = (const float*)d_in[1];
  const float* offset_b = (const float*)d_in[2];
  const float* weight   = (const float*)d_in[3];
  const float* gamma    = (const float*)d_in[4];
  float* out = (float*)d_out;
  float* wsf = (float*)d_ws;
  float*    off    = wsf;                               // 5308416 f32
  ushort_t* xt     = (ushort_t*)(wsf + 5308416);        // 4194304 f16
  ushort_t* wfrag  = (ushort_t*)(wsf + 7405568);        // 110592 f16
  ushort_t* w2frag = (ushort_t*)(wsf + 7460864);        // 165888 f16

  hipLaunchKernelGGL(prep, dim3(648), dim3(256), 0, stream,
                     offset_w, weight, w2frag, wfrag);
  hipLaunchKernelGGL(transpose_x, dim3(1024), dim3(256), 0, stream, x, xt);
  hipLaunchKernelGGL(offconv, dim3(1024), dim3(256), 0, stream,
                     xt, w2frag, offset_b, off);
  hipLaunchKernelGGL(deform, dim3(1024), dim3(256), 0, stream,
                     x, xt, off, wfrag, gamma, out);
}

// Round 3
// 208.139 us; speedup vs baseline: 1.3601x; 1.0791x over previous
//
#include <hip/hip_runtime.h>
#include <cmath>

// Problem constants (B=1): x (1,4,64,128,128) f32
#define Cc 64
#define Hh 128
#define Ww 128
#define HW_ 16384
#define THW_ 65536
#define CHW_ 1048576
#define NT 27

typedef unsigned short ushort_t;
typedef _Float16 f16x2 __attribute__((ext_vector_type(2)));
typedef _Float16 f16x8 __attribute__((ext_vector_type(8)));
typedef __fp16 fp16x2_alt __attribute__((ext_vector_type(2)));
typedef float floatx4 __attribute__((ext_vector_type(4)));
typedef unsigned uint4v __attribute__((ext_vector_type(4)));

union U32H2 { unsigned u; f16x2 h; };

static __device__ inline ushort_t f2h(float f) {
  union { _Float16 h; ushort_t u; } v;
  v.h = (_Float16)f;
  return v.u;
}

static __device__ inline unsigned pk2(float a) {
  union { fp16x2_alt h; unsigned u; } v;
  v.h = __builtin_amdgcn_cvt_pkrtz(a, a);
  return v.u;
}

#if defined(__has_builtin)
#if __has_builtin(__builtin_amdgcn_make_buffer_rsrc) && __has_builtin(__builtin_amdgcn_raw_buffer_load_b32) && __has_builtin(__builtin_amdgcn_raw_buffer_load_b128)
#define USE_BUF 1
#endif
#endif
#ifndef USE_BUF
#define USE_BUF 0
#endif

struct XtBuf {
#if USE_BUF
  __amdgpu_buffer_rsrc_t r;
#else
  const char* p;
#endif
};

static __device__ inline XtBuf mkbuf(const ushort_t* xt) {
  XtBuf b;
#if USE_BUF
  b.r = __builtin_amdgcn_make_buffer_rsrc((void*)xt, (short)0, 8388608, 0x00020000);
#else
  b.p = (const char*)xt;
#endif
  return b;
}

static __device__ inline uint4v xload4(const XtBuf& b, unsigned voff) {
#if USE_BUF
  return __builtin_amdgcn_raw_buffer_load_b128(b.r, (int)voff, 0, 0);
#else
  return *(const uint4v*)(b.p + voff);
#endif
}

// ws layout (floats):
//   [0, 5308416)                    (unused; was off)
//   xt     : [5308416, +2097152)    x -> [t][h][w][c] f16 (4194304 ushorts)
//   wfrag  : [7405568, +55296)      deform weight B-frags, 110592 f16
//   w2frag : [7460864, +82944)      offconv weight B-frags, 165888 f16

__global__ __launch_bounds__(256) void prep(
    const float* __restrict__ offset_w,
    const float* __restrict__ weight,
    ushort_t* __restrict__ w2frag,
    ushort_t* __restrict__ wfrag)
{
  int e = blockIdx.x * 256 + threadIdx.x;
  if (e < 165888) {   // offconv: 27 taps x 6 oc-tiles x 2 khalf x 64 lanes x 8
    int j = e & 7, ln = (e >> 3) & 63, kh2 = (e >> 9) & 1, r = e >> 10;
    int ot = r % 6, k = r / 6;
    int oc = ot * 16 + (ln & 15);
    int c  = kh2 * 32 + (ln >> 4) * 8 + j;
    float v = (oc < 81) ? offset_w[(oc * 64 + c) * 27 + k] : 0.f;
    w2frag[e] = f2h(v);
  }
  if (e < 110592) {   // deform: 27 taps x 4 oc-tiles x 2 khalf x 64 lanes x 8
    int j = e & 7, ln = (e >> 3) & 63, kh2 = (e >> 9) & 1, r = e >> 10;
    int ot = r & 3, k = r >> 2;
    int o = ot * 16 + (ln & 15);
    int c = kh2 * 32 + (ln >> 4) * 8 + j;
    wfrag[e] = f2h(weight[(o * 64 + c) * 27 + k]);
  }
}

__global__ __launch_bounds__(256) void transpose_x(
    const float* __restrict__ x, ushort_t* __restrict__ xt)
{
  __shared__ float tile[64][65];
  int b = blockIdx.x;
  int wblk = b & 1;
  int th = b >> 1;
  int h = th & 127;
  int t = th >> 7;
  int w0 = wblk * 64;
  int lane = threadIdx.x & 63;
  int quad = threadIdx.x >> 6;
  #pragma unroll
  for (int cc = 0; cc < 16; ++cc) {
    int c = cc * 4 + quad;
    tile[c][lane] = x[t * CHW_ + c * HW_ + h * Ww + w0 + lane];
  }
  __syncthreads();
  #pragma unroll
  for (int ww = 0; ww < 16; ++ww) {
    int w = ww * 4 + quad;
    xt[(size_t)(t * HW_ + h * Ww + w0 + w) * 64 + lane] = f2h(tile[lane][w]);
  }
}

// One trilinear site: data chunk (uint4v = 8 f16 ch) x packed weight, into
// even/odd f16x2 accumulator chains (bit-identical order to the 107us kernel).
#define SITE(W, D, A0, A1, A2, A3) \
  { U32H2 wu; wu.u = (W); U32H2 q0, q1, q2, q3; \
    q0.u = (D)[0]; q1.u = (D)[1]; q2.u = (D)[2]; q3.u = (D)[3]; \
    A0 += wu.h * q0.h; A1 += wu.h * q1.h; A2 += wu.h * q2.h; A3 += wu.h * q3.h; }

// Fused offset-conv + deformable conv. One block = 64 positions.
// Phase 1: offconv GEMM off[81][64] -> Obuf in LDS (accumulator write is
//   intra-wave: wave computes exactly its own 16 positions' offsets).
// Phase 2: deform (half-tap software pipeline, dwordx4 gathers, register
//   staging pinned by sched_barrier fences); dt/dh/dw read from Obuf LDS
//   (removes the 21 MB off round trip and its per-tap HBM/L3 latency).
__global__ __launch_bounds__(256, 4) void fused(
    const float* __restrict__ x,
    const ushort_t* __restrict__ xt,
    const ushort_t* __restrict__ w2frag,
    const float* __restrict__ ob,
    const ushort_t* __restrict__ wfrag,
    const float* __restrict__ gamma,
    float* __restrict__ out)
{
  __shared__ __align__(16) char lds[38480];
  ushort_t* S = (ushort_t*)lds;               // [64 pos][72 f16] = 9216
  unsigned* msite0 = (unsigned*)(lds + 9216);
  unsigned* msite1 = (unsigned*)(lds + 11264);
  unsigned* mwt0   = (unsigned*)(lds + 13312);
  unsigned* mwt1   = (unsigned*)(lds + 15360);
  float* Obuf = (float*)(lds + 17408);        // [81 oc][65] f32 = 21060
  float* Dbuf = (float*)lds;                  // [64 oc][65] f32 (epilogue alias)
  int lane = threadIdx.x & 63;
  int wavei = __builtin_amdgcn_readfirstlane(threadIdx.x >> 6);
  int quad = lane >> 4;
  int m16 = lane & 15;
  int g8 = lane >> 3;
  unsigned coff = (unsigned)((lane & 7) * 16);
  int bid0 = blockIdx.x;
  int p0 = ((bid0 & 7) * 128 + (bid0 >> 3)) * 64;   // XCD swizzle (1024 % 8 == 0)
  int t = p0 >> 14;
  int h = (p0 >> 7) & 127;
  int w0 = p0 & 127;
  XtBuf xb = mkbuf(xt);

  // ---------------- Phase 1: offset conv ----------------
  {
    floatx4 acc[6];
    #pragma unroll
    for (int i = 0; i < 6; ++i) acc[i] = (floatx4){0.f, 0.f, 0.f, 0.f};

    uint4v pd[2];

    auto issue = [&](int k) {
      int kt = k / 9, kh = (k / 3) % 3, kw = k % 3;
      int ts = t + kt - 1, hs = h + kh - 1;
      int tsc = min(max(ts, 0), 3);
      int hsc = min(max(hs, 0), 127);
      int sbase = tsc * HW_ + hsc * Ww;
      #pragma unroll
      for (int b = 0; b < 2; ++b) {
        int prow = wavei * 16 + b * 8 + g8;
        int wc = w0 + prow + kw - 1;
        int wcc = min(max(wc, 0), 127);
        pd[b] = xload4(xb, ((unsigned)(sbase + wcc) << 7) + coff);
      }
    };

    issue(0);
    #pragma unroll 1
    for (int k = 0; k < NT; ++k) {
      int kt = k / 9, kh = (k / 3) % 3, kw = k % 3;
      int ts = t + kt - 1, hs = h + kh - 1;
      bool rowok = ((unsigned)ts < 4u) && ((unsigned)hs < 128u);
      #pragma unroll
      for (int b = 0; b < 2; ++b) {
        int prow = wavei * 16 + b * 8 + g8;
        int wc = w0 + prow + kw - 1;
        bool ok = rowok && ((unsigned)wc < 128u);
        uint4v v = pd[b];
        if (!ok) v = (uint4v){0u, 0u, 0u, 0u};
        *(uint4v*)((char*)S + prow * 144 + coff) = v;
      }
      if (k + 1 < NT) issue(k + 1);
      const ushort_t* srow = S + (wavei * 16 + m16) * 72 + quad * 8;
      f16x8 af0 = *(const f16x8*)srow;
      f16x8 af1 = *(const f16x8*)(srow + 32);
      #pragma unroll
      for (int ot = 0; ot < 6; ++ot) {
        const ushort_t* wb = w2frag + (size_t)((k * 6 + ot) * 2) * 512 + lane * 8;
        f16x8 b0 = *(const f16x8*)(wb);
        f16x8 b1 = *(const f16x8*)(wb + 512);
        acc[ot] = __builtin_amdgcn_mfma_f32_16x16x32_f16(af0, b0, acc[ot], 0, 0, 0);
        acc[ot] = __builtin_amdgcn_mfma_f32_16x16x32_f16(af1, b1, acc[ot], 0, 0, 0);
      }
    }
    // accumulators -> Obuf (+bias); intra-wave (own 16 positions only)
    #pragma unroll
    for (int ot = 0; ot < 6; ++ot) {
      int oc = ot * 16 + m16;
      if (oc < 81) {
        float bv = ob[oc];
        #pragma unroll
        for (int r = 0; r < 4; ++r)
          Obuf[oc * 65 + wavei * 16 + quad * 4 + r] = acc[ot][r] + bv;
      }
    }
  }

  // ---------------- Phase 2: deform ----------------
  floatx4 acc[4];
  #pragma unroll
  for (int i = 0; i < 4; ++i) acc[i] = (floatx4){0.f, 0.f, 0.f, 0.f};

  int pl = wavei * 16 + m16;
  int aq = quad >> 1, bq = quad & 1;
  int rowA = wavei * 16 + g8;
  int rowB = rowA + 8;

  uint4v stA[8], stB[8];

  auto meta = [&](int kk, float dtv, float dhv, float dwv) {
    unsigned* ms = (kk & 1) ? msite1 : msite0;
    unsigned* mw = (kk & 1) ? mwt1 : mwt0;
    int kt = kk / 9, kh = (kk / 3) % 3, kw = kk % 3;
    float tf = (float)(t + kt - 1) + dtv;
    float hf = (float)(h + kh - 1) + dhv;
    float wf = (float)(w0 + pl + kw - 1) + dwv;
    float tF = floorf(tf), hF = floorf(hf), wF = floorf(wf);
    float lt = tf - tF, lh_ = hf - hF, lw_ = wf - wF;
    int t0 = (int)tF, h0 = (int)hF, wq_ = (int)wF;
    int ti = t0 + aq;
    float wt_ = (aq ? lt : 1.f - lt) * (((unsigned)ti < 4u) ? 1.f : 0.f);
    int tic = min(max(ti, 0), 3);
    int hi = h0 + bq;
    float wh_ = (bq ? lh_ : 1.f - lh_) * (((unsigned)hi < 128u) ? 1.f : 0.f);
    int hic = min(max(hi, 0), 127);
    int base2 = tic * HW_ + hic * Ww;
    float bw = wt_ * wh_;
    int wi0 = wq_;
    float ww0 = (1.f - lw_) * (((unsigned)wi0 < 128u) ? 1.f : 0.f);
    int wi0c = min(max(wi0, 0), 127);
    int wi1 = wq_ + 1;
    float ww1 = lw_ * (((unsigned)wi1 < 128u) ? 1.f : 0.f);
    int wi1c = min(max(wi1, 0), 127);
    uint2 sp_;
    sp_.x = (unsigned)(base2 + wi0c) << 7;
    sp_.y = (unsigned)(base2 + wi1c) << 7;
    *(uint2*)&ms[pl * 8 + quad * 2] = sp_;
    uint2 wp_;
    wp_.x = pk2(bw * ww0);
    wp_.y = pk2(bw * ww1);
    *(uint2*)&mw[pl * 8 + quad * 2] = wp_;
  };

  auto issueA = [&](int kk) {
    const unsigned* ms = (kk & 1) ? msite1 : msite0;
    const uint4* sp = (const uint4*)&ms[rowA * 8];
    uint4 s0 = sp[0], s1 = sp[1];
    stA[0] = xload4(xb, s0.x + coff);
    stA[1] = xload4(xb, s0.y + coff);
    stA[2] = xload4(xb, s0.z + coff);
    stA[3] = xload4(xb, s0.w + coff);
    stA[4] = xload4(xb, s1.x + coff);
    stA[5] = xload4(xb, s1.y + coff);
    stA[6] = xload4(xb, s1.z + coff);
    stA[7] = xload4(xb, s1.w + coff);
  };
  auto issueB = [&](int kk) {
    const unsigned* ms = (kk & 1) ? msite1 : msite0;
    const uint4* sp = (const uint4*)&ms[rowB * 8];
    uint4 s0 = sp[0], s1 = sp[1];
    stB[0] = xload4(xb, s0.x + coff);
    stB[1] = xload4(xb, s0.y + coff);
    stB[2] = xload4(xb, s0.z + coff);
    stB[3] = xload4(xb, s0.w + coff);
    stB[4] = xload4(xb, s1.x + coff);
    stB[5] = xload4(xb, s1.y + coff);
    stB[6] = xload4(xb, s1.z + coff);
    stB[7] = xload4(xb, s1.w + coff);
  };

  auto consumeA = [&](int kk) {
    const unsigned* mw = (kk & 1) ? mwt1 : mwt0;
    const uint4* wp = (const uint4*)&mw[rowA * 8];
    uint4 w03 = wp[0], w47 = wp[1];
    U32H2 z; z.u = 0;
    f16x2 e0 = z.h, e1 = z.h, e2 = z.h, e3 = z.h;
    f16x2 o0 = z.h, o1 = z.h, o2 = z.h, o3 = z.h;
    SITE(w03.x, stA[0], e0, e1, e2, e3)
    SITE(w03.y, stA[1], o0, o1, o2, o3)
    SITE(w03.z, stA[2], e0, e1, e2, e3)
    SITE(w03.w, stA[3], o0, o1, o2, o3)
    SITE(w47.x, stA[4], e0, e1, e2, e3)
    SITE(w47.y, stA[5], o0, o1, o2, o3)
    SITE(w47.z, stA[6], e0, e1, e2, e3)
    SITE(w47.w, stA[7], o0, o1, o2, o3)
    U32H2 r0, r1, r2, r3;
    r0.h = e0 + o0; r1.h = e1 + o1; r2.h = e2 + o2; r3.h = e3 + o3;
    uint4v res = {r0.u, r1.u, r2.u, r3.u};
    *(uint4v*)((char*)S + rowA * 144 + coff) = res;
  };
  auto consumeB = [&](int kk) {
    const unsigned* mw = (kk & 1) ? mwt1 : mwt0;
    const uint4* wp = (const uint4*)&mw[rowB * 8];
    uint4 w03 = wp[0], w47 = wp[1];
    U32H2 z; z.u = 0;
    f16x2 e0 = z.h, e1 = z.h, e2 = z.h, e3 = z.h;
    f16x2 o0 = z.h, o1 = z.h, o2 = z.h, o3 = z.h;
    SITE(w03.x, stB[0], e0, e1, e2, e3)
    SITE(w03.y, stB[1], o0, o1, o2, o3)
    SITE(w03.z, stB[2], e0, e1, e2, e3)
    SITE(w03.w, stB[3], o0, o1, o2, o3)
    SITE(w47.x, stB[4], e0, e1, e2, e3)
    SITE(w47.y, stB[5], o0, o1, o2, o3)
    SITE(w47.z, stB[6], e0, e1, e2, e3)
    SITE(w47.w, stB[7], o0, o1, o2, o3)
    U32H2 r0, r1, r2, r3;
    r0.h = e0 + o0; r1.h = e1 + o1; r2.h = e2 + o2; r3.h = e3 + o3;
    uint4v res = {r0.u, r1.u, r2.u, r3.u};
    *(uint4v*)((char*)S + rowB * 144 + coff) = res;
  };

  // prologue: meta(0) (off from LDS Obuf) then half-A(0) in flight
  {
    float dt0 = Obuf[(0 * NT + 0) * 65 + pl];
    float dh0 = Obuf[(1 * NT + 0) * 65 + pl];
    float dw0 = Obuf[(2 * NT + 0) * 65 + pl];
    meta(0, dt0, dh0, dw0);
  }
  issueA(0);

  #pragma unroll 1
  for (int k = 0; k < NT; ++k) {
    int kn = (k + 1 < NT) ? k + 1 : NT - 1;
    float dt_n = Obuf[(0 * NT + kn) * 65 + pl];
    float dh_n = Obuf[(1 * NT + kn) * 65 + pl];
    float dw_n = Obuf[(2 * NT + kn) * 65 + pl];

    issueB(k);                               // half-B in flight over consumeA+meta
    __builtin_amdgcn_sched_barrier(0);
    consumeA(k);                             // S rows [0..8)
    if (k + 1 < NT) meta(kn, dt_n, dh_n, dw_n);
    consumeB(k);                             // S rows [8..16)
    if (k + 1 < NT) issueA(kn);              // half-A(k+1) in flight over MFMAs
    __builtin_amdgcn_sched_barrier(0);

    // --- MFMA
    const ushort_t* srow = S + (wavei * 16 + m16) * 72 + quad * 8;
    f16x8 af0 = *(const f16x8*)srow;
    f16x8 af1 = *(const f16x8*)(srow + 32);
    #pragma unroll
    for (int ot = 0; ot < 4; ++ot) {
      const ushort_t* wb = wfrag + (size_t)((k * 4 + ot) * 2) * 512 + lane * 8;
      f16x8 b0 = *(const f16x8*)(wb);
      f16x8 b1 = *(const f16x8*)(wb + 512);
      acc[ot] = __builtin_amdgcn_mfma_f32_16x16x32_f16(af0, b0, acc[ot], 0, 0, 0);
      acc[ot] = __builtin_amdgcn_mfma_f32_16x16x32_f16(af1, b1, acc[ot], 0, 0, 0);
    }
  }
  __syncthreads();   // S/meta/Obuf dead; Dbuf aliases S+meta
  #pragma unroll
  for (int ot = 0; ot < 4; ++ot)
    #pragma unroll
    for (int r = 0; r < 4; ++r)
      Dbuf[(ot * 16 + m16) * 65 + wavei * 16 + quad * 4 + r] = acc[ot][r];
  __syncthreads();
  float g = gamma[0];
  for (int i = threadIdx.x; i < 64 * 64; i += 256) {
    int oc = i >> 6, p = i & 63;
    size_t oi = (size_t)t * CHW_ + (size_t)oc * HW_ + (size_t)h * Ww + w0 + p;
    out[oi] = fmaf(g, Dbuf[oc * 65 + p], x[oi]);
  }
}

extern "C" void kernel_launch(void* const* d_in, const int* in_sizes, int n_in,
                              void* d_out, int out_size, void* d_ws, size_t ws_size,
                              hipStream_t stream) {
  (void)in_sizes; (void)n_in; (void)out_size; (void)ws_size;
  const float* x        = (const float*)d_in[0];
  const float* offset_w = (const float*)d_in[1];
  const float* offset_b = (const float*)d_in[2];
  const float* weight   = (const float*)d_in[3];
  const float* gamma    = (const float*)d_in[4];
  float* out = (float*)d_out;
  float* wsf = (float*)d_ws;
  ushort_t* xt     = (ushort_t*)(wsf + 5308416);        // 4194304 f16
  ushort_t* wfrag  = (ushort_t*)(wsf + 7405568);        // 110592 f16
  ushort_t* w2frag = (ushort_t*)(wsf + 7460864);        // 165888 f16

  hipLaunchKernelGGL(prep, dim3(648), dim3(256), 0, stream,
                     offset_w, weight, w2frag, wfrag);
  hipLaunchKernelGGL(transpose_x, dim3(1024), dim3(256), 0, stream, x, xt);
  hipLaunchKernelGGL(fused, dim3(1024), dim3(256), 0, stream,
                     x, xt, w2frag, offset_b, wfrag, gamma, out);
}